// Round 4
// baseline (746.338 us; speedup 1.0000x reference)
//
#include <hip/hip_runtime.h>
#include <math.h>

#define N_TOK 16384
#define DM    2048
#define NE    64
#define TOPK  4

#define OFF_TI  0
#define OFF_TS  (N_TOK * TOPK)
#define OFF_SC  (2 * N_TOK * TOPK)
#define OFF_AUX (2 * N_TOK * TOPK + N_TOK * NE)

#define TPB   64               // tokens per block
#define DC    32               // dims per chunk per K-half (64 dims/chunk total)
#define NCH   (1024 / DC)      // 32 chunks
#define USTR  68               // u LDS row stride (R3-verified: 0 conflicts)
#define ESTR  66               // E LDS row stride (reads are broadcast anyway)
#define SU_SZ (TPB * USTR)     // 4352 floats per u buffer
#define SE_SZ (64 * ESTR)      // 4224 floats per E buffer

// Block: 1024 thr = 16 waves, 64 tokens, lane = token.
// wave (eg,kh): experts eg*8..+8, dims kh*1024..+1024 -> acc[8] (static regs only).
// BOTH u and E staged coalesced into double-buffered LDS; E read via wave-uniform
// address -> HW broadcast (no SMEM in loop, no uniformity gamble, pure DS).
// Prefetch: ONE named float4 per stream, explicitly rotated (no dynamic indexing
// -> no scratch demotion; R3's pf[c%3] caused 65 MB of spill traffic).
__global__ __launch_bounds__(1024, 4) void router_main(
    const float* __restrict__ u, const float* __restrict__ E,
    const float* __restrict__ bias, float* __restrict__ out,
    float* __restrict__ ws)
{
  __shared__ float smem[2 * SU_SZ + 2 * SE_SZ];   // 68.6 KB
  float* su = smem;                // [2][TPB][USTR]
  float* se = smem + 2 * SU_SZ;    // [2][64 dims][ESTR]

  const int tid  = threadIdx.x;
  const int lane = tid & 63;
  const int wid  = __builtin_amdgcn_readfirstlane(tid >> 6);
  const int eg   = wid & 7;
  const int kh   = wid >> 3;
  const int tok0 = blockIdx.x * TPB;

  // ---- u staging map: thread -> (token, 16B dim segment) ----
  const int stok  = tid >> 4;
  const int sdseg = tid & 15;              // 0..7 kh0, 8..15 kh1
  const int skh   = sdseg >> 3;
  const int sdsub = (sdseg & 7) * 4;
  const float* ug = u + (size_t)(tok0 + stok) * DM + skh * 1024 + sdsub;
  float* suw = su + stok * USTR + sdseg * 4;

  // ---- E staging map: thread -> (dim-local, 4 experts) ----
  const int sdl  = tid >> 4;               // 0..63: 0-31 kh0 dims, 32-63 kh1
  const int se4  = (tid & 15) * 4;
  const float* Eg = E + (size_t)((sdl >> 5) * 1024 + (sdl & 31)) * NE + se4;
  float* sew = se + sdl * ESTR + se4;

  float acc[8];
#pragma unroll
  for (int j = 0; j < 8; ++j) acc[j] = 0.f;

  // prologue: chunk 0 -> buf 0; chunk 1 in flight
  float4 pu = *(const float4*)(ug);
  float4 pe = *(const float4*)(Eg);
  *(float4*)(suw) = pu;
  *(float4*)(sew) = pe;
  pu = *(const float4*)(ug + DC);
  pe = *(const float4*)(Eg + (size_t)DC * NE);
  __syncthreads();

  for (int c = 0; c < NCH; ++c) {
    if (c + 1 < NCH) {   // stage chunk c+1 (its old readers sync'd last iter)
      const int nb = (c + 1) & 1;
      *(float4*)(suw + nb * SU_SZ) = pu;
      *(float4*)(sew + nb * SE_SZ) = pe;
      if (c + 2 < NCH) { // refill: in flight across this + next compute
        pu = *(const float4*)(ug + (c + 2) * DC);
        pe = *(const float4*)(Eg + (size_t)(c + 2) * DC * NE);
      }
    }

    // ---- compute chunk c ----
    const float* sub = su + (c & 1) * SU_SZ + lane * USTR + kh * DC;
    const float* seb = se + (c & 1) * SE_SZ + (kh * DC) * ESTR + eg * 8;
#pragma unroll
    for (int s = 0; s < 8; ++s) {
      float4 uf = *(const float4*)(sub + s * 4);   // per-lane ds_read_b128
#pragma unroll
      for (int dd = 0; dd < 4; ++dd) {
        const float uv = (dd == 0) ? uf.x : (dd == 1) ? uf.y
                       : (dd == 2) ? uf.z : uf.w;   // constant-folds
        const float* er = seb + (s * 4 + dd) * ESTR; // wave-uniform -> broadcast
        float4 ea = *(const float4*)(er);
        float4 eb = *(const float4*)(er + 4);
        acc[0] = fmaf(ea.x, uv, acc[0]);
        acc[1] = fmaf(ea.y, uv, acc[1]);
        acc[2] = fmaf(ea.z, uv, acc[2]);
        acc[3] = fmaf(ea.w, uv, acc[3]);
        acc[4] = fmaf(eb.x, uv, acc[4]);
        acc[5] = fmaf(eb.y, uv, acc[5]);
        acc[6] = fmaf(eb.z, uv, acc[6]);
        acc[7] = fmaf(eb.w, uv, acc[7]);
      }
    }
    __syncthreads();
  }

  // ---- cross-wave K-half reduction into fin[64 tok][65] (aliases smem) ----
  float* fin = smem;
  if (kh == 0) {
#pragma unroll
    for (int j = 0; j < 8; ++j) fin[lane * 65 + eg * 8 + j] = acc[j];
  }
  __syncthreads();
  if (kh == 1) {
#pragma unroll
    for (int j = 0; j < 8; ++j) fin[lane * 65 + eg * 8 + j] += acc[j];
  }
  __syncthreads();

  // ---- epilogue: wave w -> tokens w*4..+3, lane = expert (R2/R3-verified) ----
  const float be = bias[lane];
  float asum = 0.f;
#pragma unroll
  for (int tt = 0; tt < 4; ++tt) {
    const int t = wid * 4 + tt;
    float x = fin[t * 65 + lane] + be;

    float m = x;
#pragma unroll
    for (int off = 32; off > 0; off >>= 1) m = fmaxf(m, __shfl_xor(m, off));
    float p = expf(x - m);
    float s = p;
#pragma unroll
    for (int off = 32; off > 0; off >>= 1) s += __shfl_xor(s, off);
    float sc = p / s;

    out[OFF_SC + (size_t)(tok0 + t) * NE + lane] = sc;
    asum += sc;

    float v = sc;
#pragma unroll
    for (int k = 0; k < TOPK; ++k) {
      float bv = v;
      int   bi = lane;
#pragma unroll
      for (int off = 32; off > 0; off >>= 1) {
        float ov = __shfl_xor(bv, off);
        int   oi = __shfl_xor(bi, off);
        if (ov > bv || (ov == bv && oi < bi)) { bv = ov; bi = oi; }
      }
      if (lane == k) {
        out[OFF_TI + (size_t)(tok0 + t) * TOPK + k] = (float)bi;
        out[OFF_TS + (size_t)(tok0 + t) * TOPK + k] = bv;
      }
      if (lane == bi) v = -INFINITY;
    }
  }
  atomicAdd(&ws[lane], asum);   // per-expert partial for aux loss
}

__global__ void router_aux(const float* __restrict__ ws, float* __restrict__ out)
{
  const int lane = threadIdx.x & 63;
  float m = ws[lane] * (1.0f / N_TOK);
  float v = m * m;
#pragma unroll
  for (int off = 32; off > 0; off >>= 1) v += __shfl_xor(v, off);
  if (lane == 0) out[OFF_AUX] = v * (float)NE;
}

extern "C" void kernel_launch(void* const* d_in, const int* in_sizes, int n_in,
                              void* d_out, int out_size, void* d_ws, size_t ws_size,
                              hipStream_t stream) {
  const float* u    = (const float*)d_in[0];
  const float* E    = (const float*)d_in[1];
  const float* bias = (const float*)d_in[2];
  float* out = (float*)d_out;
  float* ws  = (float*)d_ws;

  hipMemsetAsync(ws, 0, NE * sizeof(float), stream);
  router_main<<<N_TOK / TPB, 1024, 0, stream>>>(u, E, bias, out, ws);
  router_aux<<<1, 64, 0, stream>>>(ws, out);
}

// Round 5
// 615.166 us; speedup vs baseline: 1.2132x; 1.2132x over previous
//
#include <hip/hip_runtime.h>
#include <math.h>

#define N_TOK 16384
#define DM    2048
#define NE    64
#define TOPK  4

#define OFF_TI  0
#define OFF_TS  (N_TOK * TOPK)
#define OFF_SC  (2 * N_TOK * TOPK)
#define OFF_AUX (2 * N_TOK * TOPK + N_TOK * NE)

#define TPB   64               // tokens per block
#define NTH   512              // 8 waves
#define KQ    512              // dims per K-quarter (4-way split-K)
#define DCQ   16               // dims per chunk per quarter (64 dims/chunk total)
#define NCH   32               // chunks
#define STR   65               // LDS row stride (odd -> column reads 2-way = free)
#define SU_SZ (64 * STR)       // 4160 floats per u buffer
#define SE_SZ (64 * STR)       // 4160 floats per E buffer

// 8 fmacs into acc row ai from two float4 E values, scalar u value v.
// All indices compile-time -> stays in registers (R3 lesson: no dynamic idx).
#define FMA8(ai, v, ea, eb) \
  acc[ai][0]=fmaf((ea).x,(v),acc[ai][0]); acc[ai][1]=fmaf((ea).y,(v),acc[ai][1]); \
  acc[ai][2]=fmaf((ea).z,(v),acc[ai][2]); acc[ai][3]=fmaf((ea).w,(v),acc[ai][3]); \
  acc[ai][4]=fmaf((eb).x,(v),acc[ai][4]); acc[ai][5]=fmaf((eb).y,(v),acc[ai][5]); \
  acc[ai][6]=fmaf((eb).z,(v),acc[ai][6]); acc[ai][7]=fmaf((eb).w,(v),acc[ai][7]);

// Block: 512 thr = 8 waves, 64 tokens. Wave (w,kq): expert half w*32, K-quarter
// kq*512. Lane (tq,eq): tokens 4tq..4tq+3 x experts w*32+eq*8..+7 -> acc[4][8].
// Per-lane LDS cost: u 0.5 B/fmac + E 1 B/fmac -> per-CU DS ~33k cyc < VALU 65k.
// 256 blocks = 1/CU, 8 waves/CU.
__global__ __launch_bounds__(NTH, 4) void router_main(
    const float* __restrict__ u, const float* __restrict__ E,
    const float* __restrict__ bias, float* __restrict__ out,
    float* __restrict__ ws)
{
  __shared__ float smem[2 * SU_SZ + 2 * SE_SZ];   // 66.6 KB
  float* su = smem;                 // [2][64 tok][STR] dims: kq*16+d
  float* se = smem + 2 * SU_SZ;     // [2][64 rows][STR] row kq*16+d, 64 experts

  const int tid  = threadIdx.x;
  const int lane = tid & 63;
  const int wid  = __builtin_amdgcn_readfirstlane(tid >> 6);
  const int w    = wid & 1;        // expert half (32 experts)
  const int kq   = wid >> 1;       // K quarter
  const int tq   = lane & 15;      // token quad -> tokens 4tq..4tq+3
  const int eq   = lane >> 4;      // expert octet within half
  const int tok0 = blockIdx.x * TPB;

  // ---- u staging: thread -> token (tid>>3), float4 slots p and p+8 ----
  const int stok = tid >> 3;
  const int p    = tid & 7;
  const float* ug0 = u + (size_t)(tok0 + stok) * DM + (p >> 2) * KQ + (p & 3) * 4;
  const float* ug1 = u + (size_t)(tok0 + stok) * DM + (((p + 8) >> 2)) * KQ + ((p + 8) & 3) * 4;
  float* suw = su + stok * STR + p * 4;   // slots at +0 and +32

  // ---- E staging: thread -> rows r1 (0..31) and r1+32, 4 experts ----
  const int r1 = tid >> 4;
  const int e4 = (tid & 15) * 4;
  const float* Eg0 = E + (size_t)((r1 >> 4) * KQ + (r1 & 15)) * NE + e4;
  const float* Eg1 = E + (size_t)((((r1 + 32) >> 4)) * KQ + (r1 & 15)) * NE + e4;
  float* sew = se + r1 * STR + e4;        // rows at +0 and +32*STR

  float acc[4][8];
#pragma unroll
  for (int i = 0; i < 4; ++i)
#pragma unroll
    for (int j = 0; j < 8; ++j) acc[i][j] = 0.f;

  // prologue: chunk 0 -> buf 0, chunk 1 in registers
  float4 pu0 = *(const float4*)(ug0);
  float4 pu1 = *(const float4*)(ug1);
  float4 pe0 = *(const float4*)(Eg0);
  float4 pe1 = *(const float4*)(Eg1);
  *(float4*)(suw)            = pu0;
  *(float4*)(suw + 32)       = pu1;
  *(float4*)(sew)            = pe0;
  *(float4*)(sew + 32 * STR) = pe1;
  pu0 = *(const float4*)(ug0 + DCQ);
  pu1 = *(const float4*)(ug1 + DCQ);
  pe0 = *(const float4*)(Eg0 + DCQ * NE);
  pe1 = *(const float4*)(Eg1 + DCQ * NE);
  __syncthreads();

  for (int c = 0; c < NCH; ++c) {
    if (c + 1 < NCH) {   // stage chunk c+1 (its buffer's readers sync'd already)
      const int nb = (c + 1) & 1;
      *(float4*)(suw + nb * SU_SZ)            = pu0;
      *(float4*)(suw + nb * SU_SZ + 32)       = pu1;
      *(float4*)(sew + nb * SE_SZ)            = pe0;
      *(float4*)(sew + nb * SE_SZ + 32 * STR) = pe1;
      if (c + 2 < NCH) {
        pu0 = *(const float4*)(ug0 + (c + 2) * DCQ);
        pu1 = *(const float4*)(ug1 + (c + 2) * DCQ);
        pe0 = *(const float4*)(Eg0 + (size_t)(c + 2) * DCQ * NE);
        pe1 = *(const float4*)(Eg1 + (size_t)(c + 2) * DCQ * NE);
      }
    }

    // ---- compute chunk c: 16 dims of this wave's quarter ----
    const float* sur = su + (c & 1) * SU_SZ + (4 * tq) * STR + kq * DCQ;
    const float* ser = se + (c & 1) * SE_SZ + (kq * DCQ) * STR + w * 32 + eq * 8;
#pragma unroll
    for (int q = 0; q < 4; ++q) {   // 4 dims per sub-step
      float4 u0 = *(const float4*)(sur + 0 * STR + q * 4);
      float4 u1 = *(const float4*)(sur + 1 * STR + q * 4);
      float4 u2 = *(const float4*)(sur + 2 * STR + q * 4);
      float4 u3 = *(const float4*)(sur + 3 * STR + q * 4);
#pragma unroll
      for (int dd = 0; dd < 4; ++dd) {
        const float* er = ser + (q * 4 + dd) * STR;
        float4 ea = *(const float4*)(er);
        float4 eb = *(const float4*)(er + 4);
        const float v0 = (dd == 0) ? u0.x : (dd == 1) ? u0.y : (dd == 2) ? u0.z : u0.w;
        const float v1 = (dd == 0) ? u1.x : (dd == 1) ? u1.y : (dd == 2) ? u1.z : u1.w;
        const float v2 = (dd == 0) ? u2.x : (dd == 1) ? u2.y : (dd == 2) ? u2.z : u2.w;
        const float v3 = (dd == 0) ? u3.x : (dd == 1) ? u3.y : (dd == 2) ? u3.z : u3.w;
        FMA8(0, v0, ea, eb)
        FMA8(1, v1, ea, eb)
        FMA8(2, v2, ea, eb)
        FMA8(3, v3, ea, eb)
      }
    }
    __syncthreads();
  }

  // ---- 4-way split-K reduction into fin[64 tok][STR] (aliases smem) ----
  float* fin = smem;
#pragma unroll
  for (int r = 0; r < 4; ++r) {
    if (kq == r) {
#pragma unroll
      for (int i = 0; i < 4; ++i)
#pragma unroll
        for (int j = 0; j < 8; ++j) {
          const int idx = (4 * tq + i) * STR + w * 32 + eq * 8 + j;
          if (r == 0) fin[idx] = acc[i][j];
          else        fin[idx] += acc[i][j];
        }
    }
    __syncthreads();
  }

  // ---- epilogue: wave wid -> tokens wid*8..+7, lane = expert (verified) ----
  const float be = bias[lane];
  float asum = 0.f;
#pragma unroll
  for (int tt = 0; tt < 8; ++tt) {
    const int t = wid * 8 + tt;
    float x = fin[t * STR + lane] + be;

    float m = x;
#pragma unroll
    for (int off = 32; off > 0; off >>= 1) m = fmaxf(m, __shfl_xor(m, off));
    float pv = expf(x - m);
    float s = pv;
#pragma unroll
    for (int off = 32; off > 0; off >>= 1) s += __shfl_xor(s, off);
    float sc = pv / s;

    out[OFF_SC + (size_t)(tok0 + t) * NE + lane] = sc;
    asum += sc;

    float v = sc;
#pragma unroll
    for (int k = 0; k < TOPK; ++k) {
      float bv = v;
      int   bi = lane;
#pragma unroll
      for (int off = 32; off > 0; off >>= 1) {
        float ov = __shfl_xor(bv, off);
        int   oi = __shfl_xor(bi, off);
        if (ov > bv || (ov == bv && oi < bi)) { bv = ov; bi = oi; }
      }
      if (lane == k) {
        out[OFF_TI + (size_t)(tok0 + t) * TOPK + k] = (float)bi;
        out[OFF_TS + (size_t)(tok0 + t) * TOPK + k] = bv;
      }
      if (lane == bi) v = -INFINITY;
    }
  }
  atomicAdd(&ws[lane], asum);   // per-expert partial for aux loss

  (void)lane;
}

__global__ void router_aux(const float* __restrict__ ws, float* __restrict__ out)
{
  const int lane = threadIdx.x & 63;
  float m = ws[lane] * (1.0f / N_TOK);
  float v = m * m;
#pragma unroll
  for (int off = 32; off > 0; off >>= 1) v += __shfl_xor(v, off);
  if (lane == 0) out[OFF_AUX] = v * (float)NE;
}

extern "C" void kernel_launch(void* const* d_in, const int* in_sizes, int n_in,
                              void* d_out, int out_size, void* d_ws, size_t ws_size,
                              hipStream_t stream) {
  const float* u    = (const float*)d_in[0];
  const float* E    = (const float*)d_in[1];
  const float* bias = (const float*)d_in[2];
  float* out = (float*)d_out;
  float* ws  = (float*)d_ws;

  hipMemsetAsync(ws, 0, NE * sizeof(float), stream);
  router_main<<<N_TOK / TPB, NTH, 0, stream>>>(u, E, bias, out, ws);
  router_aux<<<1, 64, 0, stream>>>(ws, out);
}

// Round 6
// 499.460 us; speedup vs baseline: 1.4943x; 1.2317x over previous
//
#include <hip/hip_runtime.h>
#include <math.h>

#define N_TOK 16384
#define DM    2048
#define NE    64
#define TOPK  4

#define OFF_TI  0
#define OFF_TS  (N_TOK * TOPK)
#define OFF_SC  (2 * N_TOK * TOPK)
#define OFF_AUX (2 * N_TOK * TOPK + N_TOK * NE)

#define TPB   64               // tokens per block
#define NTH   512              // 8 waves
#define KQ    512              // dims per K-quarter (4-way split-K)
#define DCQ   16               // dims per chunk per quarter (64 dims/chunk total)
#define NCH   32               // chunks
#define STR   65               // LDS row stride (odd -> column reads 2-way = free)
#define SU_SZ (64 * STR)
#define SE_SZ (64 * STR)

#define FMA8(ai, v, ea, eb) \
  acc[ai][0]=fmaf((ea).x,(v),acc[ai][0]); acc[ai][1]=fmaf((ea).y,(v),acc[ai][1]); \
  acc[ai][2]=fmaf((ea).z,(v),acc[ai][2]); acc[ai][3]=fmaf((ea).w,(v),acc[ai][3]); \
  acc[ai][4]=fmaf((eb).x,(v),acc[ai][4]); acc[ai][5]=fmaf((eb).y,(v),acc[ai][5]); \
  acc[ai][6]=fmaf((eb).z,(v),acc[ai][6]); acc[ai][7]=fmaf((eb).w,(v),acc[ai][7]);

// R5 structure, spill-free. KEY FIX: amdgpu_waves_per_eu(2,2).
// __launch_bounds__(N, 4) only raises the MIN of waves-per-eu; LLVM's allocator
// targets the MAX of the range (default 8/EU -> 64 VGPRs) and SPILLS to get
// there (R2+R5 both: VGPR=64, WRITE_SIZE 80-92MB of scratch traffic). Grid is
// 256 blocks = 1 block/CU = 2 waves/EU anyway, so pinning (2,2) costs nothing
// and raises the cap to 256 VGPRs (need ~90).
__global__ __launch_bounds__(NTH)
__attribute__((amdgpu_waves_per_eu(2, 2)))
void router_main(
    const float* __restrict__ u, const float* __restrict__ E,
    const float* __restrict__ bias, float* __restrict__ out,
    float* __restrict__ ws)
{
  __shared__ float smem[2 * SU_SZ + 2 * SE_SZ];   // 66.6 KB
  float* su = smem;                 // [2][64 tok][STR] dims: kq*16+d
  float* se = smem + 2 * SU_SZ;     // [2][64 rows][STR] row kq*16+d, 64 experts

  const int tid  = threadIdx.x;
  const int lane = tid & 63;
  const int wid  = __builtin_amdgcn_readfirstlane(tid >> 6);
  const int w    = wid & 1;        // expert half (32 experts)
  const int kq   = wid >> 1;       // K quarter
  const int tq   = lane & 15;      // token quad -> tokens 4tq..4tq+3
  const int eq   = lane >> 4;      // expert octet within half
  const int tok0 = blockIdx.x * TPB;

  // ---- u staging: thread -> token (tid>>3), float4 slots p and p+8 ----
  const int stok = tid >> 3;
  const int p    = tid & 7;
  const float* ug0 = u + (size_t)(tok0 + stok) * DM + (p >> 2) * KQ + (p & 3) * 4;
  const float* ug1 = u + (size_t)(tok0 + stok) * DM + (((p + 8) >> 2)) * KQ + ((p + 8) & 3) * 4;
  float* suw = su + stok * STR + p * 4;   // slots at +0 and +32

  // ---- E staging: thread -> rows r1 (0..31) and r1+32, 4 experts ----
  const int r1 = tid >> 4;
  const int e4 = (tid & 15) * 4;
  const float* Eg0 = E + (size_t)((r1 >> 4) * KQ + (r1 & 15)) * NE + e4;
  const float* Eg1 = E + (size_t)((((r1 + 32) >> 4)) * KQ + (r1 & 15)) * NE + e4;
  float* sew = se + r1 * STR + e4;        // rows at +0 and +32*STR

  float acc[4][8];
#pragma unroll
  for (int i = 0; i < 4; ++i)
#pragma unroll
    for (int j = 0; j < 8; ++j) acc[i][j] = 0.f;

  // prologue: chunk 0 -> buf 0, chunk 1 in registers
  float4 pu0 = *(const float4*)(ug0);
  float4 pu1 = *(const float4*)(ug1);
  float4 pe0 = *(const float4*)(Eg0);
  float4 pe1 = *(const float4*)(Eg1);
  *(float4*)(suw)            = pu0;
  *(float4*)(suw + 32)       = pu1;
  *(float4*)(sew)            = pe0;
  *(float4*)(sew + 32 * STR) = pe1;
  pu0 = *(const float4*)(ug0 + DCQ);
  pu1 = *(const float4*)(ug1 + DCQ);
  pe0 = *(const float4*)(Eg0 + DCQ * NE);
  pe1 = *(const float4*)(Eg1 + DCQ * NE);
  __syncthreads();

  for (int c = 0; c < NCH; ++c) {
    if (c + 1 < NCH) {   // stage chunk c+1 (its buffer's readers sync'd already)
      const int nb = (c + 1) & 1;
      *(float4*)(suw + nb * SU_SZ)            = pu0;
      *(float4*)(suw + nb * SU_SZ + 32)       = pu1;
      *(float4*)(sew + nb * SE_SZ)            = pe0;
      *(float4*)(sew + nb * SE_SZ + 32 * STR) = pe1;
      if (c + 2 < NCH) {
        pu0 = *(const float4*)(ug0 + (c + 2) * DCQ);
        pu1 = *(const float4*)(ug1 + (c + 2) * DCQ);
        pe0 = *(const float4*)(Eg0 + (size_t)(c + 2) * DCQ * NE);
        pe1 = *(const float4*)(Eg1 + (size_t)(c + 2) * DCQ * NE);
      }
    }

    // ---- compute chunk c: 16 dims of this wave's quarter ----
    const float* sur = su + (c & 1) * SU_SZ + (4 * tq) * STR + kq * DCQ;
    const float* ser = se + (c & 1) * SE_SZ + (kq * DCQ) * STR + w * 32 + eq * 8;
#pragma unroll
    for (int q = 0; q < 4; ++q) {   // 4 dims per sub-step
      float4 u0 = *(const float4*)(sur + 0 * STR + q * 4);
      float4 u1 = *(const float4*)(sur + 1 * STR + q * 4);
      float4 u2 = *(const float4*)(sur + 2 * STR + q * 4);
      float4 u3 = *(const float4*)(sur + 3 * STR + q * 4);
#pragma unroll
      for (int dd = 0; dd < 4; ++dd) {
        const float* er = ser + (q * 4 + dd) * STR;
        float4 ea = *(const float4*)(er);
        float4 eb = *(const float4*)(er + 4);
        const float v0 = (dd == 0) ? u0.x : (dd == 1) ? u0.y : (dd == 2) ? u0.z : u0.w;
        const float v1 = (dd == 0) ? u1.x : (dd == 1) ? u1.y : (dd == 2) ? u1.z : u1.w;
        const float v2 = (dd == 0) ? u2.x : (dd == 1) ? u2.y : (dd == 2) ? u2.z : u2.w;
        const float v3 = (dd == 0) ? u3.x : (dd == 1) ? u3.y : (dd == 2) ? u3.z : u3.w;
        FMA8(0, v0, ea, eb)
        FMA8(1, v1, ea, eb)
        FMA8(2, v2, ea, eb)
        FMA8(3, v3, ea, eb)
      }
    }
    __syncthreads();
  }

  // ---- 4-way split-K reduction into fin[64 tok][STR] (aliases smem) ----
  float* fin = smem;
#pragma unroll
  for (int r = 0; r < 4; ++r) {
    if (kq == r) {
#pragma unroll
      for (int i = 0; i < 4; ++i)
#pragma unroll
        for (int j = 0; j < 8; ++j) {
          const int idx = (4 * tq + i) * STR + w * 32 + eq * 8 + j;
          if (r == 0) fin[idx] = acc[i][j];
          else        fin[idx] += acc[i][j];
        }
    }
    __syncthreads();
  }

  // ---- epilogue: wave wid -> tokens wid*8..+7, lane = expert (verified) ----
  const float be = bias[lane];
  float asum = 0.f;
#pragma unroll
  for (int tt = 0; tt < 8; ++tt) {
    const int t = wid * 8 + tt;
    float x = fin[t * STR + lane] + be;

    float m = x;
#pragma unroll
    for (int off = 32; off > 0; off >>= 1) m = fmaxf(m, __shfl_xor(m, off));
    float pv = expf(x - m);
    float s = pv;
#pragma unroll
    for (int off = 32; off > 0; off >>= 1) s += __shfl_xor(s, off);
    float sc = pv / s;

    out[OFF_SC + (size_t)(tok0 + t) * NE + lane] = sc;
    asum += sc;

    float v = sc;
#pragma unroll
    for (int k = 0; k < TOPK; ++k) {
      float bv = v;
      int   bi = lane;
#pragma unroll
      for (int off = 32; off > 0; off >>= 1) {
        float ov = __shfl_xor(bv, off);
        int   oi = __shfl_xor(bi, off);
        if (ov > bv || (ov == bv && oi < bi)) { bv = ov; bi = oi; }
      }
      if (lane == k) {
        out[OFF_TI + (size_t)(tok0 + t) * TOPK + k] = (float)bi;
        out[OFF_TS + (size_t)(tok0 + t) * TOPK + k] = bv;
      }
      if (lane == bi) v = -INFINITY;
    }
  }
  atomicAdd(&ws[lane], asum);   // per-expert partial for aux loss
}

__global__ void router_aux(const float* __restrict__ ws, float* __restrict__ out)
{
  const int lane = threadIdx.x & 63;
  float m = ws[lane] * (1.0f / N_TOK);
  float v = m * m;
#pragma unroll
  for (int off = 32; off > 0; off >>= 1) v += __shfl_xor(v, off);
  if (lane == 0) out[OFF_AUX] = v * (float)NE;
}

extern "C" void kernel_launch(void* const* d_in, const int* in_sizes, int n_in,
                              void* d_out, int out_size, void* d_ws, size_t ws_size,
                              hipStream_t stream) {
  const float* u    = (const float*)d_in[0];
  const float* E    = (const float*)d_in[1];
  const float* bias = (const float*)d_in[2];
  float* out = (float*)d_out;
  float* ws  = (float*)d_ws;

  hipMemsetAsync(ws, 0, NE * sizeof(float), stream);
  router_main<<<N_TOK / TPB, NTH, 0, stream>>>(u, E, bias, out, ws);
  router_aux<<<1, 64, 0, stream>>>(ws, out);
}